// Round 1
// baseline (1494.194 us; speedup 1.0000x reference)
//
#include <hip/hip_runtime.h>
#include <math.h>

#define N_NODES 50000
#define E_EDGES 800000
#define IN_F 128
#define HID_F 64
#define OUT_F 32

// ---------------- degree kernels ----------------
__global__ __launch_bounds__(256) void deg_init_kernel(float* degs, float* degt, int n) {
    int t = blockIdx.x * 256 + threadIdx.x;
    if (t < n) { degs[t] = 1.0f; degt[t] = 1.0f; }   // self-loop contributes 1 to both
}

__global__ __launch_bounds__(256) void deg_count_kernel(const int* __restrict__ ei0,
                                                        const int* __restrict__ ei1,
                                                        float* degs, float* degt, int e) {
    int t = blockIdx.x * 256 + threadIdx.x;
    if (t < e) {
        atomicAdd(&degs[ei0[t]], 1.0f);
        atomicAdd(&degt[ei1[t]], 1.0f);
    }
}

__global__ __launch_bounds__(256) void deg_inv_kernel(float* degs, float* degt, int n) {
    int t = blockIdx.x * 256 + threadIdx.x;
    if (t < n) {
        degs[t] = 1.0f / sqrtf(degs[t]);
        degt[t] = 1.0f / sqrtf(degt[t]);
    }
}

// ---------------- linear: Y = (relu?)X @ W^T + b ----------------
// W is [OUTF][INF] row-major. 16 nodes per block; W transposed into LDS with
// +1 pad (stride OUTF+1) so the o-contiguous wave read is conflict-free.
template <int INF, int OUTF, bool RELU_IN>
__global__ __launch_bounds__(256) void linear_kernel(const float* __restrict__ X,
                                                     const float* __restrict__ W,
                                                     const float* __restrict__ b,
                                                     float* __restrict__ Y, int n) {
    constexpr int NT = 16;            // nodes per block
    constexpr int NGRP = 256 / OUTF;  // thread groups
    constexpr int NPG = NT / NGRP;    // nodes per group
    constexpr int WSTR = OUTF + 1;
    __shared__ float Wt[INF * WSTR];
    __shared__ float xs[NT * INF];
    __shared__ float bs[OUTF];

    int tid = threadIdx.x;
    for (int idx = tid; idx < INF * OUTF; idx += 256) {
        int o = idx / INF, k = idx % INF;   // INF is pow2 -> shifts
        Wt[k * WSTR + o] = W[idx];          // coalesced global read
    }
    if (tid < OUTF) bs[tid] = b[tid];
    int node0 = blockIdx.x * NT;
    for (int idx = tid; idx < NT * INF; idx += 256) {
        int i = idx / INF, k = idx % INF;
        int nidx = node0 + i;
        float v = (nidx < n) ? X[nidx * INF + k] : 0.0f;
        if (RELU_IN) v = fmaxf(v, 0.0f);
        xs[i * INF + k] = v;
    }
    __syncthreads();

    int o = tid % OUTF;
    int grp = tid / OUTF;
    float acc[NPG];
#pragma unroll
    for (int j = 0; j < NPG; ++j) acc[j] = bs[o];
#pragma unroll 4
    for (int k = 0; k < INF; ++k) {
        float w = Wt[k * WSTR + o];         // conflict-free (pad)
#pragma unroll
        for (int j = 0; j < NPG; ++j)
            acc[j] += w * xs[(grp + j * NGRP) * INF + k];   // LDS broadcast
    }
#pragma unroll
    for (int j = 0; j < NPG; ++j) {
        int nidx = node0 + grp + j * NGRP;
        if (nidx < n) Y[nidx * OUTF + o] = acc[j];          // coalesced
    }
}

// ---------------- aggregation ----------------
// self-loop term doubles as output init (ws/d_out are poisoned 0xAA each call)
template <int F>
__global__ __launch_bounds__(256) void agg_init_kernel(const float* __restrict__ xw,
                                                       const float* __restrict__ dsi,
                                                       const float* __restrict__ dti,
                                                       float* __restrict__ out, int n) {
    int t = blockIdx.x * 256 + threadIdx.x;
    if (t >= n * F) return;
    int v = t / F;
    out[t] = dsi[v] * dti[v] * xw[t];
}

// one (edge, feature) per thread; wave handles 64/F edges with 256B-contiguous
// gather + scatter rows. norm = dsi[ei0]*dti[ei1] in BOTH directions.
template <int F, bool FWD>
__global__ __launch_bounds__(256) void agg_edge_kernel(const float* __restrict__ xw,
                                                       float* __restrict__ out,
                                                       const int* __restrict__ ei0,
                                                       const int* __restrict__ ei1,
                                                       const float* __restrict__ dsi,
                                                       const float* __restrict__ dti,
                                                       int e_total) {
    int t = blockIdx.x * 256 + threadIdx.x;
    int e = t / F;
    int f = t % F;
    if (e >= e_total) return;
    int a = ei0[e];
    int c = ei1[e];
    float w = dsi[a] * dti[c];
    int g = FWD ? a : c;   // gather node
    int s = FWD ? c : a;   // scatter node
    atomicAdd(&out[s * F + f], w * xw[g * F + f]);
}

// ---------------- final combine ----------------
__global__ __launch_bounds__(256) void combine_kernel(float* __restrict__ outp,
                                                      const float* __restrict__ slog,
                                                      const float* __restrict__ tlog,
                                                      const float* __restrict__ ns,
                                                      const float* __restrict__ nt_,
                                                      int n) {  // n = N*OUT
    int t = blockIdx.x * 256 + threadIdx.x;
    if (t >= n) return;
    outp[t]     = outp[t]     + ns[t]  * expf(slog[t]) / 5.0f;
    outp[n + t] = outp[n + t] + nt_[t] * expf(tlog[t]) / 5.0f;
}

// ---------------- per-encoder driver ----------------
static void run_encoder(const float* X, const float* W1, const float* b1,
                        const float* W2, const float* b2, bool fwd1, float* outbuf,
                        const int* ei0, const int* ei1, float* dsi, float* dti,
                        float* xw1, float* h1, float* xw2, hipStream_t stream) {
    dim3 blk(256);
    int lin_grid = (N_NODES + 15) / 16;
    int agg1_grid = (N_NODES * HID_F + 255) / 256;
    int agg2_grid = (N_NODES * OUT_F + 255) / 256;
    int edge1_grid = (E_EDGES * HID_F + 255) / 256;   // 200000
    int edge2_grid = (E_EDGES * OUT_F + 255) / 256;   // 100000

    // conv1: linear -> self-loop init -> edge scatter (direction fwd1)
    linear_kernel<IN_F, HID_F, false><<<lin_grid, blk, 0, stream>>>(X, W1, b1, xw1, N_NODES);
    agg_init_kernel<HID_F><<<agg1_grid, blk, 0, stream>>>(xw1, dsi, dti, h1, N_NODES);
    if (fwd1)
        agg_edge_kernel<HID_F, true><<<edge1_grid, blk, 0, stream>>>(xw1, h1, ei0, ei1, dsi, dti, E_EDGES);
    else
        agg_edge_kernel<HID_F, false><<<edge1_grid, blk, 0, stream>>>(xw1, h1, ei0, ei1, dsi, dti, E_EDGES);

    // conv2: relu fused into linear's X read; direction flipped vs conv1
    linear_kernel<HID_F, OUT_F, true><<<lin_grid, blk, 0, stream>>>(h1, W2, b2, xw2, N_NODES);
    agg_init_kernel<OUT_F><<<agg2_grid, blk, 0, stream>>>(xw2, dsi, dti, outbuf, N_NODES);
    if (!fwd1)
        agg_edge_kernel<OUT_F, true><<<edge2_grid, blk, 0, stream>>>(xw2, outbuf, ei0, ei1, dsi, dti, E_EDGES);
    else
        agg_edge_kernel<OUT_F, false><<<edge2_grid, blk, 0, stream>>>(xw2, outbuf, ei0, ei1, dsi, dti, E_EDGES);
}

extern "C" void kernel_launch(void* const* d_in, const int* in_sizes, int n_in,
                              void* d_out, int out_size, void* d_ws, size_t ws_size,
                              hipStream_t stream) {
    const float* s       = (const float*)d_in[0];
    const float* t       = (const float*)d_in[1];
    const int*   ei      = (const int*)d_in[2];
    const float* noise_s = (const float*)d_in[3];
    const float* noise_t = (const float*)d_in[4];
    const float* sm1_W = (const float*)d_in[5];  const float* sm1_b = (const float*)d_in[6];
    const float* sm2_W = (const float*)d_in[7];  const float* sm2_b = (const float*)d_in[8];
    const float* sl1_W = (const float*)d_in[9];  const float* sl1_b = (const float*)d_in[10];
    const float* sl2_W = (const float*)d_in[11]; const float* sl2_b = (const float*)d_in[12];
    const float* tm1_W = (const float*)d_in[13]; const float* tm1_b = (const float*)d_in[14];
    const float* tm2_W = (const float*)d_in[15]; const float* tm2_b = (const float*)d_in[16];
    const float* tl1_W = (const float*)d_in[17]; const float* tl1_b = (const float*)d_in[18];
    const float* tl2_W = (const float*)d_in[19]; const float* tl2_b = (const float*)d_in[20];

    const int* ei0 = ei;            // sources
    const int* ei1 = ei + E_EDGES;  // targets

    // workspace layout (floats): 2N + 2*(N*64) + N*32 + 2*(N*32) = 226N ≈ 45.2 MB
    float* ws   = (float*)d_ws;
    float* dsi  = ws;                       // N   (deg_s -> inv sqrt, in place)
    float* dti  = dsi + N_NODES;            // N
    float* xw1  = dti + N_NODES;            // N*64 (reused per encoder)
    float* h1   = xw1 + N_NODES * HID_F;    // N*64
    float* xw2  = h1  + N_NODES * HID_F;    // N*32
    float* slog = xw2 + N_NODES * OUT_F;    // N*32
    float* tlog = slog + N_NODES * OUT_F;   // N*32

    float* s_out = (float*)d_out;                    // [N,32] -> holds s_mu then final
    float* t_out = (float*)d_out + N_NODES * OUT_F;  // [N,32] -> holds t_mu then final

    dim3 blk(256);
    // degrees (shared across all 8 convs; norm = dsi[ei0]*dti[ei1] both ways)
    deg_init_kernel<<<(N_NODES + 255) / 256, blk, 0, stream>>>(dsi, dti, N_NODES);
    deg_count_kernel<<<(E_EDGES + 255) / 256, blk, 0, stream>>>(ei0, ei1, dsi, dti, E_EDGES);
    deg_inv_kernel<<<(N_NODES + 255) / 256, blk, 0, stream>>>(dsi, dti, N_NODES);

    // source encoders: conv1 forward, conv2 backward
    run_encoder(s, sm1_W, sm1_b, sm2_W, sm2_b, true,  s_out, ei0, ei1, dsi, dti, xw1, h1, xw2, stream);
    run_encoder(s, sl1_W, sl1_b, sl2_W, sl2_b, true,  slog,  ei0, ei1, dsi, dti, xw1, h1, xw2, stream);
    // target encoders: conv1 backward, conv2 forward
    run_encoder(t, tm1_W, tm1_b, tm2_W, tm2_b, false, t_out, ei0, ei1, dsi, dti, xw1, h1, xw2, stream);
    run_encoder(t, tl1_W, tl1_b, tl2_W, tl2_b, false, tlog,  ei0, ei1, dsi, dti, xw1, h1, xw2, stream);

    combine_kernel<<<(N_NODES * OUT_F + 255) / 256, blk, 0, stream>>>(
        s_out, slog, tlog, noise_s, noise_t, N_NODES * OUT_F);
}

// Round 2
// 895.395 us; speedup vs baseline: 1.6688x; 1.6688x over previous
//
#include <hip/hip_runtime.h>
#include <math.h>

#define N_NODES 50000
#define E_EDGES 800000
#define IN_F 128
#define HID_F 64
#define OUT_F 32

// ================= CSR build =================
__global__ __launch_bounds__(256) void zero2_kernel(int* a, int* b, int n) {
    int t = blockIdx.x * 256 + threadIdx.x;
    if (t < n) { a[t] = 0; b[t] = 0; }
}

__global__ __launch_bounds__(256) void count_kernel(const int* __restrict__ ei0,
                                                    const int* __restrict__ ei1,
                                                    int* cnt_fwd /*by dst=ei1*/,
                                                    int* cnt_bwd /*by src=ei0*/, int e) {
    int t = blockIdx.x * 256 + threadIdx.x;
    if (t < e) {
        atomicAdd(&cnt_fwd[ei1[t]], 1);   // indeg
        atomicAdd(&cnt_bwd[ei0[t]], 1);   // outdeg
    }
}

// single-block chunked exclusive scan (n=50k: 49 chunks x 10 LDS steps, ~µs)
__global__ __launch_bounds__(1024) void scan_kernel(const int* __restrict__ cnt,
                                                    int* __restrict__ offs, int n) {
    __shared__ int sh[1024];
    __shared__ int carry_s;
    int tid = threadIdx.x;
    if (tid == 0) carry_s = 0;
    __syncthreads();
    for (int base = 0; base < n; base += 1024) {
        int i = base + tid;
        int v = (i < n) ? cnt[i] : 0;
        sh[tid] = v;
        __syncthreads();
        for (int off = 1; off < 1024; off <<= 1) {
            int add = (tid >= off) ? sh[tid - off] : 0;
            __syncthreads();
            sh[tid] += add;
            __syncthreads();
        }
        int incl = sh[tid];
        int carry = carry_s;
        if (i < n) offs[i] = carry + incl - v;  // exclusive
        __syncthreads();
        if (tid == 1023) carry_s = carry + incl;
        __syncthreads();
    }
    if (tid == 0) offs[n] = carry_s;
}

// dsi = (outdeg+1)^-1/2, dti = (indeg+1)^-1/2; cnt arrays become fill cursors
__global__ __launch_bounds__(256) void degcur_kernel(int* cnt_fwd, int* cnt_bwd,
                                                     const int* __restrict__ offs_fwd,
                                                     const int* __restrict__ offs_bwd,
                                                     float* dsi, float* dti, int n) {
    int v = blockIdx.x * 256 + threadIdx.x;
    if (v < n) {
        dti[v] = rsqrtf((float)(cnt_fwd[v] + 1));
        dsi[v] = rsqrtf((float)(cnt_bwd[v] + 1));
        cnt_fwd[v] = offs_fwd[v];
        cnt_bwd[v] = offs_bwd[v];
    }
}

__global__ __launch_bounds__(256) void fill_kernel(const int* __restrict__ ei0,
                                                   const int* __restrict__ ei1,
                                                   int* cur_fwd, int* cur_bwd,
                                                   int* pay_fwd, int* pay_bwd, int e) {
    int t = blockIdx.x * 256 + threadIdx.x;
    if (t < e) {
        int a = ei0[t], c = ei1[t];
        pay_fwd[atomicAdd(&cur_fwd[c], 1)] = a;  // node c's in-edges, payload=src
        pay_bwd[atomicAdd(&cur_bwd[a], 1)] = c;  // node a's out-edges, payload=dst
    }
}

// ================= linear: Y[:,ocol0:+OUTF] = (relu?)X[:,icol0:+INF] @ W^T + b =========
template <int INF, int OUTF, int ISTR, int OSTR, bool RELU_IN>
__global__ __launch_bounds__(256) void linear_kernel(const float* __restrict__ X,
                                                     const float* __restrict__ W,
                                                     const float* __restrict__ b,
                                                     float* __restrict__ Y,
                                                     int icol0, int ocol0, int n) {
    constexpr int NT = 16;            // nodes per block
    constexpr int NGRP = 256 / OUTF;  // thread groups
    constexpr int NPG = NT / NGRP;    // nodes per group
    constexpr int WSTR = OUTF + 1;
    __shared__ float Wt[INF * WSTR];
    __shared__ float xs[NT * INF];
    __shared__ float bs[OUTF];

    int tid = threadIdx.x;
    for (int idx = tid; idx < INF * OUTF; idx += 256) {
        int o = idx / INF, k = idx % INF;
        Wt[k * WSTR + o] = W[idx];
    }
    if (tid < OUTF) bs[tid] = b[tid];
    int node0 = blockIdx.x * NT;
    for (int idx = tid; idx < NT * INF; idx += 256) {
        int i = idx / INF, k = idx % INF;
        int nidx = node0 + i;
        float v = (nidx < n) ? X[nidx * ISTR + icol0 + k] : 0.0f;
        if (RELU_IN) v = fmaxf(v, 0.0f);
        xs[i * INF + k] = v;
    }
    __syncthreads();

    int o = tid % OUTF;
    int grp = tid / OUTF;
    float acc[NPG];
#pragma unroll
    for (int j = 0; j < NPG; ++j) acc[j] = bs[o];
#pragma unroll 4
    for (int k = 0; k < INF; ++k) {
        float w = Wt[k * WSTR + o];
#pragma unroll
        for (int j = 0; j < NPG; ++j)
            acc[j] += w * xs[(grp + j * NGRP) * INF + k];
    }
#pragma unroll
    for (int j = 0; j < NPG; ++j) {
        int nidx = node0 + grp + j * NGRP;
        if (nidx < n) Y[nidx * OSTR + ocol0 + o] = acc[j];
    }
}

// ================= pull aggregation (atomic-free) =================
// out[v] = fac_self[v] * ( fac_other[v]*xw[v] + sum_{e: list(v)} fac_other[pay]*xw[pay] )
// float4/thread: TPN = F/4 threads per node. FINAL fuses reparametrize:
// cols 0:32 = mu, 32:64 = logstd; partner lane is +8 within the wave.
template <int F, bool FINAL>
__global__ __launch_bounds__(256) void pull_agg_kernel(const float* __restrict__ xw,
                                                       float* __restrict__ out,
                                                       const int* __restrict__ offs,
                                                       const int* __restrict__ pay,
                                                       const float* __restrict__ fac_self,
                                                       const float* __restrict__ fac_other,
                                                       const float* __restrict__ noise,
                                                       int n) {
    constexpr int TPN = F / 4;
    constexpr int NPB = 256 / TPN;
    const float4* xw4 = (const float4*)xw;
    int ln = threadIdx.x / TPN;
    int f4 = threadIdx.x % TPN;
    int v = blockIdx.x * NPB + ln;
    if (v >= n) return;
    int start = offs[v], end = offs[v + 1];

    float w0 = fac_other[v];                 // self-loop as virtual edge
    float4 x = xw4[v * TPN + f4];
    float4 acc = make_float4(w0 * x.x, w0 * x.y, w0 * x.z, w0 * x.w);

    int i = start;
    for (; i + 1 < end; i += 2) {            // 2x unroll for load ILP
        int s0 = pay[i], s1 = pay[i + 1];
        float wa = fac_other[s0], wb = fac_other[s1];
        float4 xa = xw4[s0 * TPN + f4];
        float4 xb = xw4[s1 * TPN + f4];
        acc.x += wa * xa.x; acc.y += wa * xa.y; acc.z += wa * xa.z; acc.w += wa * xa.w;
        acc.x += wb * xb.x; acc.y += wb * xb.y; acc.z += wb * xb.z; acc.w += wb * xb.w;
    }
    if (i < end) {
        int s0 = pay[i];
        float wa = fac_other[s0];
        float4 xa = xw4[s0 * TPN + f4];
        acc.x += wa * xa.x; acc.y += wa * xa.y; acc.z += wa * xa.z; acc.w += wa * xa.w;
    }
    float fs = fac_self[v];
    acc.x *= fs; acc.y *= fs; acc.z *= fs; acc.w *= fs;

    if (!FINAL) {
        ((float4*)out)[v * TPN + f4] = acc;
    } else {
        int lane = threadIdx.x & 63;         // TPN=16: node spans lanes [b, b+16)
        float l0 = __shfl(acc.x, lane + 8);  // partner holds features 32+4*f4..+3
        float l1 = __shfl(acc.y, lane + 8);
        float l2 = __shfl(acc.z, lane + 8);
        float l3 = __shfl(acc.w, lane + 8);
        if (f4 < 8) {
            float4 nz = ((const float4*)noise)[v * 8 + f4];
            float4 r;
            r.x = acc.x + nz.x * expf(l0) * 0.2f;
            r.y = acc.y + nz.y * expf(l1) * 0.2f;
            r.z = acc.z + nz.z * expf(l2) * 0.2f;
            r.w = acc.w + nz.w * expf(l3) * 0.2f;
            ((float4*)out)[v * 8 + f4] = r;
        }
    }
}

// ================= driver =================
extern "C" void kernel_launch(void* const* d_in, const int* in_sizes, int n_in,
                              void* d_out, int out_size, void* d_ws, size_t ws_size,
                              hipStream_t stream) {
    const float* s       = (const float*)d_in[0];
    const float* t       = (const float*)d_in[1];
    const int*   ei      = (const int*)d_in[2];
    const float* noise_s = (const float*)d_in[3];
    const float* noise_t = (const float*)d_in[4];
    const float* sm1_W = (const float*)d_in[5];  const float* sm1_b = (const float*)d_in[6];
    const float* sm2_W = (const float*)d_in[7];  const float* sm2_b = (const float*)d_in[8];
    const float* sl1_W = (const float*)d_in[9];  const float* sl1_b = (const float*)d_in[10];
    const float* sl2_W = (const float*)d_in[11]; const float* sl2_b = (const float*)d_in[12];
    const float* tm1_W = (const float*)d_in[13]; const float* tm1_b = (const float*)d_in[14];
    const float* tm2_W = (const float*)d_in[15]; const float* tm2_b = (const float*)d_in[16];
    const float* tl1_W = (const float*)d_in[17]; const float* tl1_b = (const float*)d_in[18];
    const float* tl2_W = (const float*)d_in[19]; const float* tl2_b = (const float*)d_in[20];

    const int* ei0 = ei;            // sources
    const int* ei1 = ei + E_EDGES;  // targets

    // ws layout: float4-sensitive buffers first (d_ws is 16B-aligned)
    float* A = (float*)d_ws;                  // N*128 (xw fused; reused as conv2 xw)
    float* B = A + N_NODES * 128;             // N*128 (h1 fused)
    float* C = A;                             // alias: conv2 input built after A free
    float* dsi = B + N_NODES * 128;           // N
    float* dti = dsi + N_NODES;               // N
    int* offs_fwd = (int*)(dti + N_NODES);    // N+1
    int* offs_bwd = offs_fwd + N_NODES + 1;   // N+1
    int* cnt_fwd  = offs_bwd + N_NODES + 1;   // N (then cursor)
    int* cnt_bwd  = cnt_fwd + N_NODES;        // N
    int* pay_fwd  = cnt_bwd + N_NODES;        // E
    int* pay_bwd  = pay_fwd + E_EDGES;        // E
    // total ≈ 59 MB

    float* s_out = (float*)d_out;                    // [N,32]
    float* t_out = (float*)d_out + N_NODES * OUT_F;  // [N,32]

    dim3 blk(256);
    int ngrid = (N_NODES + 255) / 256;
    int egrid = (E_EDGES + 255) / 256;
    int lgrid = (N_NODES + 15) / 16;
    int p128_grid = (N_NODES + 7) / 8;    // TPN=32, 8 nodes/block
    int p64_grid  = (N_NODES + 15) / 16;  // TPN=16, 16 nodes/block

    // ---- CSR + degrees (shared by all 8 convs) ----
    zero2_kernel<<<ngrid, blk, 0, stream>>>(cnt_fwd, cnt_bwd, N_NODES);
    count_kernel<<<egrid, blk, 0, stream>>>(ei0, ei1, cnt_fwd, cnt_bwd, E_EDGES);
    scan_kernel<<<1, 1024, 0, stream>>>(cnt_fwd, offs_fwd, N_NODES);
    scan_kernel<<<1, 1024, 0, stream>>>(cnt_bwd, offs_bwd, N_NODES);
    degcur_kernel<<<ngrid, blk, 0, stream>>>(cnt_fwd, cnt_bwd, offs_fwd, offs_bwd,
                                             dsi, dti, N_NODES);
    fill_kernel<<<egrid, blk, 0, stream>>>(ei0, ei1, cnt_fwd, cnt_bwd,
                                           pay_fwd, pay_bwd, E_EDGES);

    // ---- source encoders (sm+sl fused): conv1 fwd (CSR_fwd), conv2 bwd (CSR_bwd) ----
    linear_kernel<128, 64, 128, 128, false><<<lgrid, blk, 0, stream>>>(s, sm1_W, sm1_b, A, 0, 0,  N_NODES);
    linear_kernel<128, 64, 128, 128, false><<<lgrid, blk, 0, stream>>>(s, sl1_W, sl1_b, A, 0, 64, N_NODES);
    pull_agg_kernel<128, false><<<p128_grid, blk, 0, stream>>>(A, B, offs_fwd, pay_fwd, dti, dsi, nullptr, N_NODES);
    linear_kernel<64, 32, 128, 64, true><<<lgrid, blk, 0, stream>>>(B, sm2_W, sm2_b, C, 0,  0,  N_NODES);
    linear_kernel<64, 32, 128, 64, true><<<lgrid, blk, 0, stream>>>(B, sl2_W, sl2_b, C, 64, 32, N_NODES);
    pull_agg_kernel<64, true><<<p64_grid, blk, 0, stream>>>(C, s_out, offs_bwd, pay_bwd, dsi, dti, noise_s, N_NODES);

    // ---- target encoders (tm+tl fused): conv1 bwd (CSR_bwd), conv2 fwd (CSR_fwd) ----
    linear_kernel<128, 64, 128, 128, false><<<lgrid, blk, 0, stream>>>(t, tm1_W, tm1_b, A, 0, 0,  N_NODES);
    linear_kernel<128, 64, 128, 128, false><<<lgrid, blk, 0, stream>>>(t, tl1_W, tl1_b, A, 0, 64, N_NODES);
    pull_agg_kernel<128, false><<<p128_grid, blk, 0, stream>>>(A, B, offs_bwd, pay_bwd, dsi, dti, nullptr, N_NODES);
    linear_kernel<64, 32, 128, 64, true><<<lgrid, blk, 0, stream>>>(B, tm2_W, tm2_b, C, 0,  0,  N_NODES);
    linear_kernel<64, 32, 128, 64, true><<<lgrid, blk, 0, stream>>>(B, tl2_W, tl2_b, C, 64, 32, N_NODES);
    pull_agg_kernel<64, true><<<p64_grid, blk, 0, stream>>>(C, t_out, offs_fwd, pay_fwd, dti, dsi, noise_t, N_NODES);
}

// Round 3
// 712.859 us; speedup vs baseline: 2.0961x; 1.2561x over previous
//
#include <hip/hip_runtime.h>
#include <math.h>

#define N_NODES 50000
#define E_EDGES 800000
#define IN_F 128
#define HID_F 64
#define OUT_F 32
#define NCHUNKS ((N_NODES + 1023) / 1024)

// ================= CSR build =================
__global__ __launch_bounds__(256) void zero2_kernel(int* a, int* b, int n) {
    int t = blockIdx.x * 256 + threadIdx.x;
    if (t < n) { a[t] = 0; b[t] = 0; }
}

__global__ __launch_bounds__(256) void count_kernel(const int* __restrict__ ei0,
                                                    const int* __restrict__ ei1,
                                                    int* cnt_fwd /*by dst=ei1*/,
                                                    int* cnt_bwd /*by src=ei0*/, int e) {
    int t = blockIdx.x * 256 + threadIdx.x;
    if (t < e) {
        atomicAdd(&cnt_fwd[ei1[t]], 1);   // indeg
        atomicAdd(&cnt_bwd[ei0[t]], 1);   // outdeg
    }
}

// ---- grid-parallel exclusive scan: chunk scan -> partials scan -> add back ----
__global__ __launch_bounds__(1024) void scan_chunk_kernel(const int* __restrict__ cnt,
                                                          int* __restrict__ offs,
                                                          int* __restrict__ partials, int n) {
    __shared__ int sh[1024];
    int tid = threadIdx.x;
    int i = blockIdx.x * 1024 + tid;
    int v = (i < n) ? cnt[i] : 0;
    sh[tid] = v;
    __syncthreads();
    for (int off = 1; off < 1024; off <<= 1) {
        int add = (tid >= off) ? sh[tid - off] : 0;
        __syncthreads();
        sh[tid] += add;
        __syncthreads();
    }
    if (i < n) offs[i] = sh[tid] - v;          // exclusive within chunk
    if (tid == 1023) partials[blockIdx.x] = sh[tid];
}

__global__ __launch_bounds__(64) void scan_partials_kernel(int* p, int nchunks) {
    __shared__ int sh[64];
    int tid = threadIdx.x;
    int v = (tid < nchunks) ? p[tid] : 0;
    sh[tid] = v;
    __syncthreads();
    for (int off = 1; off < 64; off <<= 1) {
        int add = (tid >= off) ? sh[tid - off] : 0;
        __syncthreads();
        sh[tid] += add;
        __syncthreads();
    }
    if (tid < nchunks) p[tid] = sh[tid] - v;   // exclusive
    if (tid == 63) p[nchunks] = sh[63];        // total
}

__global__ __launch_bounds__(256) void scan_addback_kernel(int* __restrict__ offs,
                                                           const int* __restrict__ partials,
                                                           int n, int nchunks) {
    int i = blockIdx.x * 256 + threadIdx.x;
    if (i < n) offs[i] += partials[i >> 10];
    else if (i == n) offs[n] = partials[nchunks];
}

// dsi = (outdeg+1)^-1/2, dti = (indeg+1)^-1/2; cnt arrays become fill cursors
__global__ __launch_bounds__(256) void degcur_kernel(int* cnt_fwd, int* cnt_bwd,
                                                     const int* __restrict__ offs_fwd,
                                                     const int* __restrict__ offs_bwd,
                                                     float* dsi, float* dti, int n) {
    int v = blockIdx.x * 256 + threadIdx.x;
    if (v < n) {
        dti[v] = rsqrtf((float)(cnt_fwd[v] + 1));
        dsi[v] = rsqrtf((float)(cnt_bwd[v] + 1));
        cnt_fwd[v] = offs_fwd[v];
        cnt_bwd[v] = offs_bwd[v];
    }
}

// split per direction: scatter working set 3.2MB fits a 4MB XCD L2
__global__ __launch_bounds__(256) void fill_one_kernel(const int* __restrict__ key,
                                                       const int* __restrict__ pay_in,
                                                       int* cur, int* pay_out, int e) {
    int t = blockIdx.x * 256 + threadIdx.x;
    if (t < e) {
        pay_out[atomicAdd(&cur[key[t]], 1)] = pay_in[t];
    }
}

// ======= linear: Y[:,ocol0:+OUTF] = scale[v] * ((relu?)X[:,icol0:+INF] @ W^T + b) =======
template <int INF, int OUTF, int ISTR, int OSTR, bool RELU_IN>
__global__ __launch_bounds__(256) void linear_kernel(const float* __restrict__ X,
                                                     const float* __restrict__ W,
                                                     const float* __restrict__ b,
                                                     const float* __restrict__ scale,
                                                     float* __restrict__ Y,
                                                     int icol0, int ocol0, int n) {
    constexpr int NT = 16;            // nodes per block
    constexpr int NGRP = 256 / OUTF;  // thread groups
    constexpr int NPG = NT / NGRP;    // nodes per group
    constexpr int WSTR = OUTF + 1;
    __shared__ float Wt[INF * WSTR];
    __shared__ float xs[NT * INF];
    __shared__ float bs[OUTF];

    int tid = threadIdx.x;
    for (int idx = tid; idx < INF * OUTF; idx += 256) {
        int o = idx / INF, k = idx % INF;
        Wt[k * WSTR + o] = W[idx];
    }
    if (tid < OUTF) bs[tid] = b[tid];
    int node0 = blockIdx.x * NT;
    for (int idx = tid; idx < NT * INF; idx += 256) {
        int i = idx / INF, k = idx % INF;
        int nidx = node0 + i;
        float v = (nidx < n) ? X[nidx * ISTR + icol0 + k] : 0.0f;
        if (RELU_IN) v = fmaxf(v, 0.0f);
        xs[i * INF + k] = v;
    }
    __syncthreads();

    int o = tid % OUTF;
    int grp = tid / OUTF;
    float acc[NPG];
#pragma unroll
    for (int j = 0; j < NPG; ++j) acc[j] = bs[o];
#pragma unroll 4
    for (int k = 0; k < INF; ++k) {
        float w = Wt[k * WSTR + o];
#pragma unroll
        for (int j = 0; j < NPG; ++j)
            acc[j] += w * xs[(grp + j * NGRP) * INF + k];
    }
#pragma unroll
    for (int j = 0; j < NPG; ++j) {
        int nidx = node0 + grp + j * NGRP;
        if (nidx < n) Y[nidx * OSTR + ocol0 + o] = scale[nidx] * acc[j];
    }
}

// ================= pull aggregation (atomic-free, pre-scaled rows) =================
// xw rows are pre-scaled by fac_other in the linear epilogue, so:
//   out[v] = fac_self[v] * ( xw'[v] + sum_{e in list(v)} xw'[pay_e] )
// -> inner loop is pure gather+add with a pay->gather 2-level chain, 4-way unrolled.
template <int F, bool FINAL>
__global__ __launch_bounds__(256) void pull_agg_kernel(const float* __restrict__ xw,
                                                       float* __restrict__ out,
                                                       const int* __restrict__ offs,
                                                       const int* __restrict__ pay,
                                                       const float* __restrict__ fac_self,
                                                       const float* __restrict__ noise,
                                                       int n) {
    constexpr int TPN = F / 4;
    constexpr int NPB = 256 / TPN;
    const float4* xw4 = (const float4*)xw;
    int ln = threadIdx.x / TPN;
    int f4 = threadIdx.x % TPN;
    int v = blockIdx.x * NPB + ln;
    if (v >= n) return;
    int i = offs[v], end = offs[v + 1];

    float4 acc = xw4[v * TPN + f4];            // self-loop row (pre-scaled)

    for (; i + 3 < end; i += 4) {              // 4 independent gathers in flight
        int s0 = pay[i], s1 = pay[i + 1], s2 = pay[i + 2], s3 = pay[i + 3];
        float4 xa = xw4[s0 * TPN + f4];
        float4 xb = xw4[s1 * TPN + f4];
        float4 xc = xw4[s2 * TPN + f4];
        float4 xd = xw4[s3 * TPN + f4];
        acc.x += (xa.x + xb.x) + (xc.x + xd.x);
        acc.y += (xa.y + xb.y) + (xc.y + xd.y);
        acc.z += (xa.z + xb.z) + (xc.z + xd.z);
        acc.w += (xa.w + xb.w) + (xc.w + xd.w);
    }
    for (; i < end; ++i) {
        int s0 = pay[i];
        float4 xa = xw4[s0 * TPN + f4];
        acc.x += xa.x; acc.y += xa.y; acc.z += xa.z; acc.w += xa.w;
    }
    float fs = fac_self[v];
    acc.x *= fs; acc.y *= fs; acc.z *= fs; acc.w *= fs;

    if (!FINAL) {
        ((float4*)out)[v * TPN + f4] = acc;
    } else {
        int lane = threadIdx.x & 63;           // TPN=16: node spans 16 lanes
        float l0 = __shfl(acc.x, lane + 8);    // partner lane holds logstd slice
        float l1 = __shfl(acc.y, lane + 8);
        float l2 = __shfl(acc.z, lane + 8);
        float l3 = __shfl(acc.w, lane + 8);
        if (f4 < 8) {
            float4 nz = ((const float4*)noise)[v * 8 + f4];
            float4 r;
            r.x = acc.x + nz.x * expf(l0) * 0.2f;
            r.y = acc.y + nz.y * expf(l1) * 0.2f;
            r.z = acc.z + nz.z * expf(l2) * 0.2f;
            r.w = acc.w + nz.w * expf(l3) * 0.2f;
            ((float4*)out)[v * 8 + f4] = r;
        }
    }
}

// ================= driver =================
extern "C" void kernel_launch(void* const* d_in, const int* in_sizes, int n_in,
                              void* d_out, int out_size, void* d_ws, size_t ws_size,
                              hipStream_t stream) {
    const float* s       = (const float*)d_in[0];
    const float* t       = (const float*)d_in[1];
    const int*   ei      = (const int*)d_in[2];
    const float* noise_s = (const float*)d_in[3];
    const float* noise_t = (const float*)d_in[4];
    const float* sm1_W = (const float*)d_in[5];  const float* sm1_b = (const float*)d_in[6];
    const float* sm2_W = (const float*)d_in[7];  const float* sm2_b = (const float*)d_in[8];
    const float* sl1_W = (const float*)d_in[9];  const float* sl1_b = (const float*)d_in[10];
    const float* sl2_W = (const float*)d_in[11]; const float* sl2_b = (const float*)d_in[12];
    const float* tm1_W = (const float*)d_in[13]; const float* tm1_b = (const float*)d_in[14];
    const float* tm2_W = (const float*)d_in[15]; const float* tm2_b = (const float*)d_in[16];
    const float* tl1_W = (const float*)d_in[17]; const float* tl1_b = (const float*)d_in[18];
    const float* tl2_W = (const float*)d_in[19]; const float* tl2_b = (const float*)d_in[20];

    const int* ei0 = ei;            // sources
    const int* ei1 = ei + E_EDGES;  // targets

    // ws layout: float4-sensitive buffers first (d_ws is 16B-aligned)
    float* A = (float*)d_ws;                  // N*128 (conv1 xw fused; reused for conv2)
    float* B = A + N_NODES * 128;             // N*128 (h1 fused)
    float* C = A;                             // alias
    float* dsi = B + N_NODES * 128;           // N
    float* dti = dsi + N_NODES;               // N
    int* offs_fwd = (int*)(dti + N_NODES);    // N+1
    int* offs_bwd = offs_fwd + N_NODES + 1;   // N+1
    int* cnt_fwd  = offs_bwd + N_NODES + 1;   // N (then cursor)
    int* cnt_bwd  = cnt_fwd + N_NODES;        // N
    int* pay_fwd  = cnt_bwd + N_NODES;        // E
    int* pay_bwd  = pay_fwd + E_EDGES;        // E
    int* part_fwd = pay_bwd + E_EDGES;        // NCHUNKS+1
    int* part_bwd = part_fwd + NCHUNKS + 1;   // NCHUNKS+1

    float* s_out = (float*)d_out;                    // [N,32]
    float* t_out = (float*)d_out + N_NODES * OUT_F;  // [N,32]

    dim3 blk(256);
    int ngrid = (N_NODES + 255) / 256;
    int egrid = (E_EDGES + 255) / 256;
    int lgrid = (N_NODES + 15) / 16;
    int agrid = (N_NODES + 1 + 255) / 256;
    int p128_grid = (N_NODES + 7) / 8;    // TPN=32, 8 nodes/block
    int p64_grid  = (N_NODES + 15) / 16;  // TPN=16, 16 nodes/block

    // ---- CSR + degrees (shared by all 8 convs) ----
    zero2_kernel<<<ngrid, blk, 0, stream>>>(cnt_fwd, cnt_bwd, N_NODES);
    count_kernel<<<egrid, blk, 0, stream>>>(ei0, ei1, cnt_fwd, cnt_bwd, E_EDGES);
    scan_chunk_kernel<<<NCHUNKS, 1024, 0, stream>>>(cnt_fwd, offs_fwd, part_fwd, N_NODES);
    scan_chunk_kernel<<<NCHUNKS, 1024, 0, stream>>>(cnt_bwd, offs_bwd, part_bwd, N_NODES);
    scan_partials_kernel<<<1, 64, 0, stream>>>(part_fwd, NCHUNKS);
    scan_partials_kernel<<<1, 64, 0, stream>>>(part_bwd, NCHUNKS);
    scan_addback_kernel<<<agrid, blk, 0, stream>>>(offs_fwd, part_fwd, N_NODES, NCHUNKS);
    scan_addback_kernel<<<agrid, blk, 0, stream>>>(offs_bwd, part_bwd, N_NODES, NCHUNKS);
    degcur_kernel<<<ngrid, blk, 0, stream>>>(cnt_fwd, cnt_bwd, offs_fwd, offs_bwd,
                                             dsi, dti, N_NODES);
    fill_one_kernel<<<egrid, blk, 0, stream>>>(ei1, ei0, cnt_fwd, pay_fwd, E_EDGES);
    fill_one_kernel<<<egrid, blk, 0, stream>>>(ei0, ei1, cnt_bwd, pay_bwd, E_EDGES);

    // ---- source encoders (sm+sl fused): conv1 fwd pull, conv2 bwd pull ----
    // fwd pull: gather=src scaled by dsi, fac_self=dti; bwd pull: gather scaled dti, fac_self=dsi
    linear_kernel<128, 64, 128, 128, false><<<lgrid, blk, 0, stream>>>(s, sm1_W, sm1_b, dsi, A, 0, 0,  N_NODES);
    linear_kernel<128, 64, 128, 128, false><<<lgrid, blk, 0, stream>>>(s, sl1_W, sl1_b, dsi, A, 0, 64, N_NODES);
    pull_agg_kernel<128, false><<<p128_grid, blk, 0, stream>>>(A, B, offs_fwd, pay_fwd, dti, nullptr, N_NODES);
    linear_kernel<64, 32, 128, 64, true><<<lgrid, blk, 0, stream>>>(B, sm2_W, sm2_b, dti, C, 0,  0,  N_NODES);
    linear_kernel<64, 32, 128, 64, true><<<lgrid, blk, 0, stream>>>(B, sl2_W, sl2_b, dti, C, 64, 32, N_NODES);
    pull_agg_kernel<64, true><<<p64_grid, blk, 0, stream>>>(C, s_out, offs_bwd, pay_bwd, dsi, noise_s, N_NODES);

    // ---- target encoders (tm+tl fused): conv1 bwd pull, conv2 fwd pull ----
    linear_kernel<128, 64, 128, 128, false><<<lgrid, blk, 0, stream>>>(t, tm1_W, tm1_b, dti, A, 0, 0,  N_NODES);
    linear_kernel<128, 64, 128, 128, false><<<lgrid, blk, 0, stream>>>(t, tl1_W, tl1_b, dti, A, 0, 64, N_NODES);
    pull_agg_kernel<128, false><<<p128_grid, blk, 0, stream>>>(A, B, offs_bwd, pay_bwd, dsi, nullptr, N_NODES);
    linear_kernel<64, 32, 128, 64, true><<<lgrid, blk, 0, stream>>>(B, tm2_W, tm2_b, dsi, C, 0,  0,  N_NODES);
    linear_kernel<64, 32, 128, 64, true><<<lgrid, blk, 0, stream>>>(B, tl2_W, tl2_b, dsi, C, 64, 32, N_NODES);
    pull_agg_kernel<64, true><<<p64_grid, blk, 0, stream>>>(C, t_out, offs_fwd, pay_fwd, dti, noise_t, N_NODES);
}

// Round 5
// 532.265 us; speedup vs baseline: 2.8072x; 1.3393x over previous
//
#include <hip/hip_runtime.h>
#include <math.h>

#define N_NODES 50000
#define E_EDGES 800000
#define NCHUNKS ((N_NODES + 1023) / 1024)

// ================= CSR build =================
__global__ __launch_bounds__(256) void zero2_kernel(int* a, int* b, int n) {
    int t = blockIdx.x * 256 + threadIdx.x;
    if (t < n) { a[t] = 0; b[t] = 0; }
}

// count degrees AND capture per-edge rank (atomic return) -> atomic-free fill
__global__ __launch_bounds__(256) void count_rank_kernel(const int* __restrict__ ei0,
                                                         const int* __restrict__ ei1,
                                                         int* cnt_fwd, int* cnt_bwd,
                                                         int* rank_fwd, int* rank_bwd, int e) {
    int t = blockIdx.x * 256 + threadIdx.x;
    if (t < e) {
        rank_fwd[t] = atomicAdd(&cnt_fwd[ei1[t]], 1);   // indeg, rank within dst list
        rank_bwd[t] = atomicAdd(&cnt_bwd[ei0[t]], 1);   // outdeg, rank within src list
    }
}

// ---- grid-parallel exclusive scan, both directions via blockIdx.y ----
__global__ __launch_bounds__(1024) void scan_chunk2_kernel(const int* __restrict__ cnt_f,
                                                           const int* __restrict__ cnt_b,
                                                           int* __restrict__ offs_f,
                                                           int* __restrict__ offs_b,
                                                           int* __restrict__ part_f,
                                                           int* __restrict__ part_b, int n) {
    const int* cnt = blockIdx.y ? cnt_b : cnt_f;
    int* offs = blockIdx.y ? offs_b : offs_f;
    int* partials = blockIdx.y ? part_b : part_f;
    __shared__ int sh[1024];
    int tid = threadIdx.x;
    int i = blockIdx.x * 1024 + tid;
    int v = (i < n) ? cnt[i] : 0;
    sh[tid] = v;
    __syncthreads();
    for (int off = 1; off < 1024; off <<= 1) {
        int add = (tid >= off) ? sh[tid - off] : 0;
        __syncthreads();
        sh[tid] += add;
        __syncthreads();
    }
    if (i < n) offs[i] = sh[tid] - v;
    if (tid == 1023) partials[blockIdx.x] = sh[tid];
}

__global__ __launch_bounds__(64) void scan_partials2_kernel(int* part_f, int* part_b, int nchunks) {
    int* p = blockIdx.x ? part_b : part_f;
    __shared__ int sh[64];
    int tid = threadIdx.x;
    int v = (tid < nchunks) ? p[tid] : 0;
    sh[tid] = v;
    __syncthreads();
    for (int off = 1; off < 64; off <<= 1) {
        int add = (tid >= off) ? sh[tid - off] : 0;
        __syncthreads();
        sh[tid] += add;
        __syncthreads();
    }
    if (tid < nchunks) p[tid] = sh[tid] - v;
    if (tid == 63) p[nchunks] = sh[63];
}

// add-back partials for both dirs + compute inv-sqrt degree factors, one launch
__global__ __launch_bounds__(256) void addback_deg_kernel(int* __restrict__ offs_f,
                                                          int* __restrict__ offs_b,
                                                          const int* __restrict__ part_f,
                                                          const int* __restrict__ part_b,
                                                          const int* __restrict__ cnt_f,
                                                          const int* __restrict__ cnt_b,
                                                          float* dsi, float* dti,
                                                          int n, int nchunks) {
    int i = blockIdx.x * 256 + threadIdx.x;
    if (blockIdx.y == 0) {
        if (i < n) {
            offs_f[i] += part_f[i >> 10];
            dti[i] = rsqrtf((float)(cnt_f[i] + 1));
        } else if (i == n) offs_f[n] = part_f[nchunks];
    } else {
        if (i < n) {
            offs_b[i] += part_b[i >> 10];
            dsi[i] = rsqrtf((float)(cnt_b[i] + 1));
        } else if (i == n) offs_b[n] = part_b[nchunks];
    }
}

// atomic-free fill using precomputed ranks
__global__ __launch_bounds__(256) void fill_kernel(const int* __restrict__ key,
                                                   const int* __restrict__ payload,
                                                   const int* __restrict__ rank,
                                                   const int* __restrict__ offs,
                                                   int* __restrict__ pay_out, int e) {
    int t = blockIdx.x * 256 + threadIdx.x;
    if (t < e) pay_out[offs[key[t]] + rank[t]] = payload[t];
}

// ======= conv1 dual linear: A[:,0:64] = scale*(X@Wa^T+ba), A[:,64:128] = scale*(X@Wb^T+bb)
// X staged to LDS ONCE; the two weight sets run sequentially through the same LDS tile.
__global__ __launch_bounds__(256) void lin1_dual_kernel(const float* __restrict__ X,
                                                        const float* __restrict__ Wa,
                                                        const float* __restrict__ ba,
                                                        const float* __restrict__ Wb,
                                                        const float* __restrict__ bb,
                                                        const float* __restrict__ scale,
                                                        float* __restrict__ A, int n) {
    // 16 nodes/block, N_NODES % 16 == 0 -> no guards needed
    __shared__ float Wt[128 * 65];   // 33.3 KB, transposed + pad
    __shared__ float xs[16 * 128];   // 8 KB (stride 128: 2-addr/bank reads are free)
    __shared__ float bsh[64];

    int tid = threadIdx.x;
    int node0 = blockIdx.x * 16;
    // stage X: 2048 consecutive floats = 512 float4
    const float4* Xsrc = (const float4*)(X + node0 * 128);
    float4* xs4 = (float4*)xs;
    xs4[tid] = Xsrc[tid];
    xs4[tid + 256] = Xsrc[tid + 256];

    int o = tid & 63;
    int grp = tid >> 6;   // 4 groups, nodes grp + 4j

    for (int set = 0; set < 2; ++set) {
        const float* W = set ? Wb : Wa;
        const float* b = set ? bb : ba;
        __syncthreads();   // protect Wt/bsh from previous set's readers (and xs stores, set 0)
        for (int idx = tid; idx < 8192; idx += 256) {
            int oo = idx >> 7, k = idx & 127;
            Wt[k * 65 + oo] = W[idx];
        }
        if (tid < 64) bsh[tid] = b[tid];
        __syncthreads();

        float acc0 = bsh[o], acc1 = bsh[o], acc2 = bsh[o], acc3 = bsh[o];
#pragma unroll 4
        for (int k = 0; k < 128; ++k) {
            float w = Wt[k * 65 + o];
            acc0 += w * xs[(grp)      * 128 + k];
            acc1 += w * xs[(grp + 4)  * 128 + k];
            acc2 += w * xs[(grp + 8)  * 128 + k];
            acc3 += w * xs[(grp + 12) * 128 + k];
        }
        int col = set * 64 + o;
        A[(node0 + grp)      * 128 + col] = scale[node0 + grp]      * acc0;
        A[(node0 + grp + 4)  * 128 + col] = scale[node0 + grp + 4]  * acc1;
        A[(node0 + grp + 8)  * 128 + col] = scale[node0 + grp + 8]  * acc2;
        A[(node0 + grp + 12) * 128 + col] = scale[node0 + grp + 12] * acc3;
    }
}

// ======= fused conv1-aggregate + relu + conv2 dual linear =======
// pull phase: h[v] = fac_self[v] * (A'[v] + sum A'[pay]) (A' rows pre-scaled)
// h cols 0:64 = mu branch, 64:128 = logstd branch.
// then C[v, 0:32] = scale2*(relu(h_mu) @ W2a^T + b2a), C[v,32:64] = relu(h_log) @ W2b^T...
__global__ __launch_bounds__(256) void pull_lin_kernel(const float* __restrict__ xw,
                                                       float* __restrict__ C,
                                                       const int* __restrict__ offs,
                                                       const int* __restrict__ pay,
                                                       const float* __restrict__ fac_self,
                                                       const float* __restrict__ scale2,
                                                       const float* __restrict__ W2a,
                                                       const float* __restrict__ b2a,
                                                       const float* __restrict__ W2b,
                                                       const float* __restrict__ b2b, int n) {
    // 8 nodes/block (TPN=32), N_NODES % 8 == 0 -> guard-free
    __shared__ float Wt[64 * 66];   // Wt[k*66+o]=W2a[o][k]; Wt[k*66+33+o]=W2b[o][k]
    __shared__ float bsh[64];
    __shared__ float xs[8 * 132];   // pulled+relu'd h rows, stride 132

    int tid = threadIdx.x;
    // stage W2 (independent of pull; overlaps gather latency)
    for (int idx = tid; idx < 2048; idx += 256) {
        int o = idx >> 6, k = idx & 63;
        Wt[k * 66 + o]      = W2a[idx];
        Wt[k * 66 + 33 + o] = W2b[idx];
    }
    if (tid < 32) { bsh[tid] = b2a[tid]; bsh[32 + tid] = b2b[tid]; }

    int ln = tid >> 5;     // node slot 0..7
    int f4 = tid & 31;     // float4 column
    int v = blockIdx.x * 8 + ln;
    int i = offs[v], end = offs[v + 1];
    const float4* xw4 = (const float4*)xw;

    float4 acc = xw4[v * 32 + f4];            // self-loop row (pre-scaled)
    for (; i + 3 < end; i += 4) {
        int s0 = pay[i], s1 = pay[i + 1], s2 = pay[i + 2], s3 = pay[i + 3];
        float4 xa = xw4[s0 * 32 + f4];
        float4 xb = xw4[s1 * 32 + f4];
        float4 xc = xw4[s2 * 32 + f4];
        float4 xd = xw4[s3 * 32 + f4];
        acc.x += (xa.x + xb.x) + (xc.x + xd.x);
        acc.y += (xa.y + xb.y) + (xc.y + xd.y);
        acc.z += (xa.z + xb.z) + (xc.z + xd.z);
        acc.w += (xa.w + xb.w) + (xc.w + xd.w);
    }
    for (; i < end; ++i) {
        int s0 = pay[i];
        float4 xa = xw4[s0 * 32 + f4];
        acc.x += xa.x; acc.y += xa.y; acc.z += xa.z; acc.w += xa.w;
    }
    float fs = fac_self[v];
    acc.x = fmaxf(acc.x * fs, 0.0f);          // conv1 out + relu
    acc.y = fmaxf(acc.y * fs, 0.0f);
    acc.z = fmaxf(acc.z * fs, 0.0f);
    acc.w = fmaxf(acc.w * fs, 0.0f);
    *((float4*)&xs[ln * 132 + f4 * 4]) = acc;
    __syncthreads();

    // conv2 dual linear: 8 nodes x 32 outputs/branch
    // mu branch input = xs[.., 0:64]; logstd branch input = xs[.., 64:128]  (R4 bugfix)
    int n2 = tid >> 5, o = tid & 31;
    float am = bsh[o], al = bsh[32 + o];
    const float* xr = &xs[n2 * 132];
#pragma unroll 4
    for (int k = 0; k < 64; ++k) {
        am += xr[k]      * Wt[k * 66 + o];
        al += xr[64 + k] * Wt[k * 66 + 33 + o];
    }
    int vv = blockIdx.x * 8 + n2;
    float sc = scale2[vv];
    C[vv * 64 + o]      = sc * am;
    C[vv * 64 + 32 + o] = sc * al;
}

// ================= final pull + reparametrize =================
template <int F>
__global__ __launch_bounds__(256) void final_pull_kernel(const float* __restrict__ xw,
                                                         float* __restrict__ out,
                                                         const int* __restrict__ offs,
                                                         const int* __restrict__ pay,
                                                         const float* __restrict__ fac_self,
                                                         const float* __restrict__ noise,
                                                         int n) {
    constexpr int TPN = F / 4;           // 16
    constexpr int NPB = 256 / TPN;       // 16
    const float4* xw4 = (const float4*)xw;
    int ln = threadIdx.x / TPN;
    int f4 = threadIdx.x % TPN;
    int v = blockIdx.x * NPB + ln;
    if (v >= n) return;
    int i = offs[v], end = offs[v + 1];

    float4 acc = xw4[v * TPN + f4];
    for (; i + 3 < end; i += 4) {
        int s0 = pay[i], s1 = pay[i + 1], s2 = pay[i + 2], s3 = pay[i + 3];
        float4 xa = xw4[s0 * TPN + f4];
        float4 xb = xw4[s1 * TPN + f4];
        float4 xc = xw4[s2 * TPN + f4];
        float4 xd = xw4[s3 * TPN + f4];
        acc.x += (xa.x + xb.x) + (xc.x + xd.x);
        acc.y += (xa.y + xb.y) + (xc.y + xd.y);
        acc.z += (xa.z + xb.z) + (xc.z + xd.z);
        acc.w += (xa.w + xb.w) + (xc.w + xd.w);
    }
    for (; i < end; ++i) {
        int s0 = pay[i];
        float4 xa = xw4[s0 * TPN + f4];
        acc.x += xa.x; acc.y += xa.y; acc.z += xa.z; acc.w += xa.w;
    }
    float fs = fac_self[v];
    acc.x *= fs; acc.y *= fs; acc.z *= fs; acc.w *= fs;

    int lane = threadIdx.x & 63;
    float l0 = __shfl(acc.x, lane + 8);  // partner lane holds logstd slice
    float l1 = __shfl(acc.y, lane + 8);
    float l2 = __shfl(acc.z, lane + 8);
    float l3 = __shfl(acc.w, lane + 8);
    if (f4 < 8) {
        float4 nz = ((const float4*)noise)[v * 8 + f4];
        float4 r;
        r.x = acc.x + nz.x * expf(l0) * 0.2f;
        r.y = acc.y + nz.y * expf(l1) * 0.2f;
        r.z = acc.z + nz.z * expf(l2) * 0.2f;
        r.w = acc.w + nz.w * expf(l3) * 0.2f;
        ((float4*)out)[v * 8 + f4] = r;
    }
}

// ================= driver =================
extern "C" void kernel_launch(void* const* d_in, const int* in_sizes, int n_in,
                              void* d_out, int out_size, void* d_ws, size_t ws_size,
                              hipStream_t stream) {
    const float* s       = (const float*)d_in[0];
    const float* t       = (const float*)d_in[1];
    const int*   ei      = (const int*)d_in[2];
    const float* noise_s = (const float*)d_in[3];
    const float* noise_t = (const float*)d_in[4];
    const float* sm1_W = (const float*)d_in[5];  const float* sm1_b = (const float*)d_in[6];
    const float* sm2_W = (const float*)d_in[7];  const float* sm2_b = (const float*)d_in[8];
    const float* sl1_W = (const float*)d_in[9];  const float* sl1_b = (const float*)d_in[10];
    const float* sl2_W = (const float*)d_in[11]; const float* sl2_b = (const float*)d_in[12];
    const float* tm1_W = (const float*)d_in[13]; const float* tm1_b = (const float*)d_in[14];
    const float* tm2_W = (const float*)d_in[15]; const float* tm2_b = (const float*)d_in[16];
    const float* tl1_W = (const float*)d_in[17]; const float* tl1_b = (const float*)d_in[18];
    const float* tl2_W = (const float*)d_in[19]; const float* tl2_b = (const float*)d_in[20];

    const int* ei0 = ei;            // sources
    const int* ei1 = ei + E_EDGES;  // targets

    float* A = (float*)d_ws;                  // N*128 conv1 output (pre-scaled rows)
    float* C = A + N_NODES * 128;             // N*64 conv2 output (pre-scaled rows)
    float* dsi = C + N_NODES * 64;            // N
    float* dti = dsi + N_NODES;               // N
    int* offs_fwd = (int*)(dti + N_NODES);    // N+1
    int* offs_bwd = offs_fwd + N_NODES + 1;   // N+1
    int* cnt_fwd  = offs_bwd + N_NODES + 1;   // N
    int* cnt_bwd  = cnt_fwd + N_NODES;        // N
    int* rank_fwd = cnt_bwd + N_NODES;        // E
    int* rank_bwd = rank_fwd + E_EDGES;       // E
    int* pay_fwd  = rank_bwd + E_EDGES;       // E
    int* pay_bwd  = pay_fwd + E_EDGES;        // E
    int* part_fwd = pay_bwd + E_EDGES;        // NCHUNKS+1
    int* part_bwd = part_fwd + NCHUNKS + 1;   // NCHUNKS+1  (total ~52.5 MB)

    float* s_out = (float*)d_out;
    float* t_out = (float*)d_out + N_NODES * 32;

    dim3 blk(256);
    int ngrid = (N_NODES + 255) / 256;
    int egrid = (E_EDGES + 255) / 256;
    dim3 agrid((N_NODES + 1 + 255) / 256, 2);
    int lgrid  = N_NODES / 16;   // 3125
    int plgrid = N_NODES / 8;    // 6250
    int fgrid  = N_NODES / 16;   // 3125

    // ---- CSR + degrees ----
    zero2_kernel<<<ngrid, blk, 0, stream>>>(cnt_fwd, cnt_bwd, N_NODES);
    count_rank_kernel<<<egrid, blk, 0, stream>>>(ei0, ei1, cnt_fwd, cnt_bwd,
                                                 rank_fwd, rank_bwd, E_EDGES);
    scan_chunk2_kernel<<<dim3(NCHUNKS, 2), 1024, 0, stream>>>(
        cnt_fwd, cnt_bwd, offs_fwd, offs_bwd, part_fwd, part_bwd, N_NODES);
    scan_partials2_kernel<<<2, 64, 0, stream>>>(part_fwd, part_bwd, NCHUNKS);
    addback_deg_kernel<<<agrid, blk, 0, stream>>>(offs_fwd, offs_bwd, part_fwd, part_bwd,
                                                  cnt_fwd, cnt_bwd, dsi, dti,
                                                  N_NODES, NCHUNKS);
    fill_kernel<<<egrid, blk, 0, stream>>>(ei1, ei0, rank_fwd, offs_fwd, pay_fwd, E_EDGES);
    fill_kernel<<<egrid, blk, 0, stream>>>(ei0, ei1, rank_bwd, offs_bwd, pay_bwd, E_EDGES);

    // ---- source encoders (mu+logstd fused): conv1 fwd pull, conv2 bwd pull ----
    lin1_dual_kernel<<<lgrid, blk, 0, stream>>>(s, sm1_W, sm1_b, sl1_W, sl1_b, dsi, A, N_NODES);
    pull_lin_kernel<<<plgrid, blk, 0, stream>>>(A, C, offs_fwd, pay_fwd, dti, dti,
                                                sm2_W, sm2_b, sl2_W, sl2_b, N_NODES);
    final_pull_kernel<64><<<fgrid, blk, 0, stream>>>(C, s_out, offs_bwd, pay_bwd, dsi,
                                                     noise_s, N_NODES);

    // ---- target encoders: conv1 bwd pull, conv2 fwd pull ----
    lin1_dual_kernel<<<lgrid, blk, 0, stream>>>(t, tm1_W, tm1_b, tl1_W, tl1_b, dti, A, N_NODES);
    pull_lin_kernel<<<plgrid, blk, 0, stream>>>(A, C, offs_bwd, pay_bwd, dsi, dsi,
                                                tm2_W, tm2_b, tl2_W, tl2_b, N_NODES);
    final_pull_kernel<64><<<fgrid, blk, 0, stream>>>(C, t_out, offs_fwd, pay_fwd, dti,
                                                     noise_t, N_NODES);
}

// Round 6
// 445.971 us; speedup vs baseline: 3.3504x; 1.1935x over previous
//
#include <hip/hip_runtime.h>
#include <hip/hip_fp16.h>
#include <math.h>

#define N_NODES 50000
#define E_EDGES 800000
#define NCHUNKS ((N_NODES + 1023) / 1024)

// ================= CSR build =================
__global__ __launch_bounds__(256) void zero2_kernel(int* a, int* b, int n) {
    int t = blockIdx.x * 256 + threadIdx.x;
    if (t < n) { a[t] = 0; b[t] = 0; }
}

// count degrees AND capture per-edge rank (atomic return) -> atomic-free fill
__global__ __launch_bounds__(256) void count_rank_kernel(const int* __restrict__ ei0,
                                                         const int* __restrict__ ei1,
                                                         int* cnt_fwd, int* cnt_bwd,
                                                         int* rank_fwd, int* rank_bwd, int e) {
    int t = blockIdx.x * 256 + threadIdx.x;
    if (t < e) {
        rank_fwd[t] = atomicAdd(&cnt_fwd[ei1[t]], 1);   // indeg, rank within dst list
        rank_bwd[t] = atomicAdd(&cnt_bwd[ei0[t]], 1);   // outdeg, rank within src list
    }
}

// ---- grid-parallel exclusive scan, both directions via blockIdx.y ----
__global__ __launch_bounds__(1024) void scan_chunk2_kernel(const int* __restrict__ cnt_f,
                                                           const int* __restrict__ cnt_b,
                                                           int* __restrict__ offs_f,
                                                           int* __restrict__ offs_b,
                                                           int* __restrict__ part_f,
                                                           int* __restrict__ part_b, int n) {
    const int* cnt = blockIdx.y ? cnt_b : cnt_f;
    int* offs = blockIdx.y ? offs_b : offs_f;
    int* partials = blockIdx.y ? part_b : part_f;
    __shared__ int sh[1024];
    int tid = threadIdx.x;
    int i = blockIdx.x * 1024 + tid;
    int v = (i < n) ? cnt[i] : 0;
    sh[tid] = v;
    __syncthreads();
    for (int off = 1; off < 1024; off <<= 1) {
        int add = (tid >= off) ? sh[tid - off] : 0;
        __syncthreads();
        sh[tid] += add;
        __syncthreads();
    }
    if (i < n) offs[i] = sh[tid] - v;
    if (tid == 1023) partials[blockIdx.x] = sh[tid];
}

__global__ __launch_bounds__(64) void scan_partials2_kernel(int* part_f, int* part_b, int nchunks) {
    int* p = blockIdx.x ? part_b : part_f;
    __shared__ int sh[64];
    int tid = threadIdx.x;
    int v = (tid < nchunks) ? p[tid] : 0;
    sh[tid] = v;
    __syncthreads();
    for (int off = 1; off < 64; off <<= 1) {
        int add = (tid >= off) ? sh[tid - off] : 0;
        __syncthreads();
        sh[tid] += add;
        __syncthreads();
    }
    if (tid < nchunks) p[tid] = sh[tid] - v;
    if (tid == 63) p[nchunks] = sh[63];
}

// add-back partials for both dirs + compute inv-sqrt degree factors, one launch
__global__ __launch_bounds__(256) void addback_deg_kernel(int* __restrict__ offs_f,
                                                          int* __restrict__ offs_b,
                                                          const int* __restrict__ part_f,
                                                          const int* __restrict__ part_b,
                                                          const int* __restrict__ cnt_f,
                                                          const int* __restrict__ cnt_b,
                                                          float* dsi, float* dti,
                                                          int n, int nchunks) {
    int i = blockIdx.x * 256 + threadIdx.x;
    if (blockIdx.y == 0) {
        if (i < n) {
            offs_f[i] += part_f[i >> 10];
            dti[i] = rsqrtf((float)(cnt_f[i] + 1));
        } else if (i == n) offs_f[n] = part_f[nchunks];
    } else {
        if (i < n) {
            offs_b[i] += part_b[i >> 10];
            dsi[i] = rsqrtf((float)(cnt_b[i] + 1));
        } else if (i == n) offs_b[n] = part_b[nchunks];
    }
}

// atomic-free fill using precomputed ranks; payload fits ushort (N < 65536)
__global__ __launch_bounds__(256) void fill_kernel(const int* __restrict__ key,
                                                   const int* __restrict__ payload,
                                                   const int* __restrict__ rank,
                                                   const int* __restrict__ offs,
                                                   unsigned short* __restrict__ pay_out, int e) {
    int t = blockIdx.x * 256 + threadIdx.x;
    if (t < e) pay_out[offs[key[t]] + rank[t]] = (unsigned short)payload[t];
}

// ======= conv1 dual linear -> fp16 A rows (pre-scaled) =======
// A[:,0:64] = scale*(X@Wa^T+ba), A[:,64:128] = scale*(X@Wb^T+bb)
__global__ __launch_bounds__(256) void lin1_dual_kernel(const float* __restrict__ X,
                                                        const float* __restrict__ Wa,
                                                        const float* __restrict__ ba,
                                                        const float* __restrict__ Wb,
                                                        const float* __restrict__ bb,
                                                        const float* __restrict__ scale,
                                                        __half* __restrict__ A, int n) {
    // 16 nodes/block, N_NODES % 16 == 0 -> no guards needed
    __shared__ float Wt[128 * 65];   // 33.3 KB, transposed + pad
    __shared__ float xs[16 * 128];   // 8 KB
    __shared__ float bsh[64];

    int tid = threadIdx.x;
    int node0 = blockIdx.x * 16;
    const float4* Xsrc = (const float4*)(X + node0 * 128);
    float4* xs4 = (float4*)xs;
    xs4[tid] = Xsrc[tid];
    xs4[tid + 256] = Xsrc[tid + 256];

    int o = tid & 63;
    int grp = tid >> 6;   // 4 groups, nodes grp + 4j

    for (int set = 0; set < 2; ++set) {
        const float* W = set ? Wb : Wa;
        const float* b = set ? bb : ba;
        __syncthreads();
        for (int idx = tid; idx < 8192; idx += 256) {
            int oo = idx >> 7, k = idx & 127;
            Wt[k * 65 + oo] = W[idx];
        }
        if (tid < 64) bsh[tid] = b[tid];
        __syncthreads();

        float acc0 = bsh[o], acc1 = bsh[o], acc2 = bsh[o], acc3 = bsh[o];
#pragma unroll 4
        for (int k = 0; k < 128; ++k) {
            float w = Wt[k * 65 + o];
            acc0 += w * xs[(grp)      * 128 + k];
            acc1 += w * xs[(grp + 4)  * 128 + k];
            acc2 += w * xs[(grp + 8)  * 128 + k];
            acc3 += w * xs[(grp + 12) * 128 + k];
        }
        int col = set * 64 + o;
        A[(node0 + grp)      * 128 + col] = __float2half(scale[node0 + grp]      * acc0);
        A[(node0 + grp + 4)  * 128 + col] = __float2half(scale[node0 + grp + 4]  * acc1);
        A[(node0 + grp + 8)  * 128 + col] = __float2half(scale[node0 + grp + 8]  * acc2);
        A[(node0 + grp + 12) * 128 + col] = __float2half(scale[node0 + grp + 12] * acc3);
    }
}

__device__ inline void acc_h8(float* acc, uint4 u) {
    const __half2* h = (const __half2*)&u;
    float2 f0 = __half22float2(h[0]);
    float2 f1 = __half22float2(h[1]);
    float2 f2 = __half22float2(h[2]);
    float2 f3 = __half22float2(h[3]);
    acc[0] += f0.x; acc[1] += f0.y; acc[2] += f1.x; acc[3] += f1.y;
    acc[4] += f2.x; acc[5] += f2.y; acc[6] += f3.x; acc[7] += f3.y;
}

// ======= fused conv1-aggregate + relu + conv2 dual linear (fp16 in, fp16 out) =======
// 16 nodes/block; TPN=16 lanes/node, 16B (8 halves) per lane per gathered row.
__global__ __launch_bounds__(256) void pull_lin_kernel(const __half* __restrict__ xw,
                                                       __half* __restrict__ C,
                                                       const int* __restrict__ offs,
                                                       const unsigned short* __restrict__ pay,
                                                       const float* __restrict__ fac_self,
                                                       const float* __restrict__ scale2,
                                                       const float* __restrict__ W2a,
                                                       const float* __restrict__ b2a,
                                                       const float* __restrict__ W2b,
                                                       const float* __restrict__ b2b, int n) {
    __shared__ float Wt[64 * 66];   // Wt[k*66+o]=W2a[o][k]; Wt[k*66+33+o]=W2b[o][k]
    __shared__ float bsh[64];
    __shared__ float xs[16 * 132];  // pulled+relu'd h rows (fp32), stride 132

    int tid = threadIdx.x;
    for (int idx = tid; idx < 2048; idx += 256) {   // overlaps gather latency
        int o = idx >> 6, k = idx & 63;
        Wt[k * 66 + o]      = W2a[idx];
        Wt[k * 66 + 33 + o] = W2b[idx];
    }
    if (tid < 32) { bsh[tid] = b2a[tid]; bsh[32 + tid] = b2b[tid]; }

    int ln = tid >> 4;     // node slot 0..15
    int f4 = tid & 15;     // uint4 column (8 halves)
    int v = blockIdx.x * 16 + ln;
    int i = offs[v], end = offs[v + 1];
    const uint4* xw16 = (const uint4*)xw;           // row stride = 16 uint4

    float acc[8] = {0, 0, 0, 0, 0, 0, 0, 0};
    acc_h8(acc, xw16[v * 16 + f4]);                 // self-loop row (pre-scaled)
    for (; i + 3 < end; i += 4) {                   // 4 independent gathers in flight
        int s0 = pay[i], s1 = pay[i + 1], s2 = pay[i + 2], s3 = pay[i + 3];
        uint4 ua = xw16[s0 * 16 + f4];
        uint4 ub = xw16[s1 * 16 + f4];
        uint4 uc = xw16[s2 * 16 + f4];
        uint4 ud = xw16[s3 * 16 + f4];
        acc_h8(acc, ua); acc_h8(acc, ub); acc_h8(acc, uc); acc_h8(acc, ud);
    }
    for (; i < end; ++i) acc_h8(acc, xw16[pay[i] * 16 + f4]);

    float fs = fac_self[v];
    float4 a0, a1;
    a0.x = fmaxf(acc[0] * fs, 0.0f); a0.y = fmaxf(acc[1] * fs, 0.0f);
    a0.z = fmaxf(acc[2] * fs, 0.0f); a0.w = fmaxf(acc[3] * fs, 0.0f);
    a1.x = fmaxf(acc[4] * fs, 0.0f); a1.y = fmaxf(acc[5] * fs, 0.0f);
    a1.z = fmaxf(acc[6] * fs, 0.0f); a1.w = fmaxf(acc[7] * fs, 0.0f);
    *(float4*)&xs[ln * 132 + f4 * 8]     = a0;
    *(float4*)&xs[ln * 132 + f4 * 8 + 4] = a1;
    __syncthreads();

    // conv2 dual linear: 16 nodes x 32 outputs/branch; thread: nodes nn, nn+8
    int nn = tid >> 5, o = tid & 31;
    const float* x0 = &xs[nn * 132];
    const float* x1 = &xs[(nn + 8) * 132];
    float am0 = bsh[o], al0 = bsh[32 + o];
    float am1 = am0,    al1 = al0;
#pragma unroll 4
    for (int k = 0; k < 64; ++k) {
        float wm = Wt[k * 66 + o], wl = Wt[k * 66 + 33 + o];
        am0 += x0[k] * wm;  al0 += x0[64 + k] * wl;
        am1 += x1[k] * wm;  al1 += x1[64 + k] * wl;
    }
    int v0 = blockIdx.x * 16 + nn;
    int v1 = v0 + 8;
    float sc0 = scale2[v0], sc1 = scale2[v1];
    C[v0 * 64 + o]      = __float2half(sc0 * am0);
    C[v0 * 64 + 32 + o] = __float2half(sc0 * al0);
    C[v1 * 64 + o]      = __float2half(sc1 * am1);
    C[v1 * 64 + 32 + o] = __float2half(sc1 * al1);
}

// ================= final pull + reparametrize (fp16 C in, fp32 out) =================
// TPN=8 lanes/node (8 halves = 16B per lane), 32 nodes/block.
__global__ __launch_bounds__(256) void final_pull_kernel(const __half* __restrict__ xw,
                                                         float* __restrict__ out,
                                                         const int* __restrict__ offs,
                                                         const unsigned short* __restrict__ pay,
                                                         const float* __restrict__ fac_self,
                                                         const float* __restrict__ noise,
                                                         int n) {
    const uint4* xw16 = (const uint4*)xw;           // row stride = 8 uint4 (64 halves)
    int ln = threadIdx.x >> 3;
    int f4 = threadIdx.x & 7;
    int v = blockIdx.x * 32 + ln;
    if (v >= n) return;
    int i = offs[v], end = offs[v + 1];

    float acc[8] = {0, 0, 0, 0, 0, 0, 0, 0};
    acc_h8(acc, xw16[v * 8 + f4]);
    for (; i + 3 < end; i += 4) {
        int s0 = pay[i], s1 = pay[i + 1], s2 = pay[i + 2], s3 = pay[i + 3];
        uint4 ua = xw16[s0 * 8 + f4];
        uint4 ub = xw16[s1 * 8 + f4];
        uint4 uc = xw16[s2 * 8 + f4];
        uint4 ud = xw16[s3 * 8 + f4];
        acc_h8(acc, ua); acc_h8(acc, ub); acc_h8(acc, uc); acc_h8(acc, ud);
    }
    for (; i < end; ++i) acc_h8(acc, xw16[pay[i] * 8 + f4]);

    float fs = fac_self[v];
#pragma unroll
    for (int j = 0; j < 8; ++j) acc[j] *= fs;

    // lanes f4 0..3 hold mu cols 8*f4..+7; partner lane f4+4 holds logstd cols 32+8*f4..+7
    int lane = threadIdx.x & 63;
    float lg[8];
#pragma unroll
    for (int j = 0; j < 8; ++j) lg[j] = __shfl(acc[j], lane + 4);
    if (f4 < 4) {
        const float4* nz4 = (const float4*)noise;
        float4 n0 = nz4[v * 8 + f4 * 2];
        float4 n1 = nz4[v * 8 + f4 * 2 + 1];
        float4 r0, r1;
        r0.x = acc[0] + n0.x * expf(lg[0]) * 0.2f;
        r0.y = acc[1] + n0.y * expf(lg[1]) * 0.2f;
        r0.z = acc[2] + n0.z * expf(lg[2]) * 0.2f;
        r0.w = acc[3] + n0.w * expf(lg[3]) * 0.2f;
        r1.x = acc[4] + n1.x * expf(lg[4]) * 0.2f;
        r1.y = acc[5] + n1.y * expf(lg[5]) * 0.2f;
        r1.z = acc[6] + n1.z * expf(lg[6]) * 0.2f;
        r1.w = acc[7] + n1.w * expf(lg[7]) * 0.2f;
        float4* o4 = (float4*)out;
        o4[v * 8 + f4 * 2]     = r0;
        o4[v * 8 + f4 * 2 + 1] = r1;
    }
}

// ================= driver =================
extern "C" void kernel_launch(void* const* d_in, const int* in_sizes, int n_in,
                              void* d_out, int out_size, void* d_ws, size_t ws_size,
                              hipStream_t stream) {
    const float* s       = (const float*)d_in[0];
    const float* t       = (const float*)d_in[1];
    const int*   ei      = (const int*)d_in[2];
    const float* noise_s = (const float*)d_in[3];
    const float* noise_t = (const float*)d_in[4];
    const float* sm1_W = (const float*)d_in[5];  const float* sm1_b = (const float*)d_in[6];
    const float* sm2_W = (const float*)d_in[7];  const float* sm2_b = (const float*)d_in[8];
    const float* sl1_W = (const float*)d_in[9];  const float* sl1_b = (const float*)d_in[10];
    const float* sl2_W = (const float*)d_in[11]; const float* sl2_b = (const float*)d_in[12];
    const float* tm1_W = (const float*)d_in[13]; const float* tm1_b = (const float*)d_in[14];
    const float* tm2_W = (const float*)d_in[15]; const float* tm2_b = (const float*)d_in[16];
    const float* tl1_W = (const float*)d_in[17]; const float* tl1_b = (const float*)d_in[18];
    const float* tl2_W = (const float*)d_in[19]; const float* tl2_b = (const float*)d_in[20];

    const int* ei0 = ei;            // sources
    const int* ei1 = ei + E_EDGES;  // targets

    __half* A = (__half*)d_ws;                // N*128 halves, conv1 out (pre-scaled)
    __half* C = A + N_NODES * 128;            // N*64 halves, conv2 out (pre-scaled)
    float* dsi = (float*)(C + N_NODES * 64);  // N
    float* dti = dsi + N_NODES;               // N
    int* offs_fwd = (int*)(dti + N_NODES);    // N+1
    int* offs_bwd = offs_fwd + N_NODES + 1;   // N+1
    int* cnt_fwd  = offs_bwd + N_NODES + 1;   // N
    int* cnt_bwd  = cnt_fwd + N_NODES;        // N
    int* rank_fwd = cnt_bwd + N_NODES;        // E
    int* rank_bwd = rank_fwd + E_EDGES;       // E
    int* part_fwd = rank_bwd + E_EDGES;       // NCHUNKS+1
    int* part_bwd = part_fwd + NCHUNKS + 1;   // NCHUNKS+1
    unsigned short* pay_fwd = (unsigned short*)(part_bwd + NCHUNKS + 1);  // E ushort
    unsigned short* pay_bwd = pay_fwd + E_EDGES;                          // E ushort

    float* s_out = (float*)d_out;
    float* t_out = (float*)d_out + N_NODES * 32;

    dim3 blk(256);
    int ngrid = (N_NODES + 255) / 256;
    int egrid = (E_EDGES + 255) / 256;
    dim3 agrid((N_NODES + 1 + 255) / 256, 2);
    int lgrid  = N_NODES / 16;        // 3125
    int plgrid = N_NODES / 16;        // 3125
    int fgrid  = (N_NODES + 31) / 32; // 1563

    // ---- CSR + degrees ----
    zero2_kernel<<<ngrid, blk, 0, stream>>>(cnt_fwd, cnt_bwd, N_NODES);
    count_rank_kernel<<<egrid, blk, 0, stream>>>(ei0, ei1, cnt_fwd, cnt_bwd,
                                                 rank_fwd, rank_bwd, E_EDGES);
    scan_chunk2_kernel<<<dim3(NCHUNKS, 2), 1024, 0, stream>>>(
        cnt_fwd, cnt_bwd, offs_fwd, offs_bwd, part_fwd, part_bwd, N_NODES);
    scan_partials2_kernel<<<2, 64, 0, stream>>>(part_fwd, part_bwd, NCHUNKS);
    addback_deg_kernel<<<agrid, blk, 0, stream>>>(offs_fwd, offs_bwd, part_fwd, part_bwd,
                                                  cnt_fwd, cnt_bwd, dsi, dti,
                                                  N_NODES, NCHUNKS);
    fill_kernel<<<egrid, blk, 0, stream>>>(ei1, ei0, rank_fwd, offs_fwd, pay_fwd, E_EDGES);
    fill_kernel<<<egrid, blk, 0, stream>>>(ei0, ei1, rank_bwd, offs_bwd, pay_bwd, E_EDGES);

    // ---- source encoders (mu+logstd fused): conv1 fwd pull, conv2 bwd pull ----
    lin1_dual_kernel<<<lgrid, blk, 0, stream>>>(s, sm1_W, sm1_b, sl1_W, sl1_b, dsi, A, N_NODES);
    pull_lin_kernel<<<plgrid, blk, 0, stream>>>(A, C, offs_fwd, pay_fwd, dti, dti,
                                                sm2_W, sm2_b, sl2_W, sl2_b, N_NODES);
    final_pull_kernel<<<fgrid, blk, 0, stream>>>(C, s_out, offs_bwd, pay_bwd, dsi,
                                                 noise_s, N_NODES);

    // ---- target encoders: conv1 bwd pull, conv2 fwd pull ----
    lin1_dual_kernel<<<lgrid, blk, 0, stream>>>(t, tm1_W, tm1_b, tl1_W, tl1_b, dti, A, N_NODES);
    pull_lin_kernel<<<plgrid, blk, 0, stream>>>(A, C, offs_bwd, pay_bwd, dsi, dsi,
                                                tm2_W, tm2_b, tl2_W, tl2_b, N_NODES);
    final_pull_kernel<<<fgrid, blk, 0, stream>>>(C, t_out, offs_fwd, pay_fwd, dti,
                                                 noise_t, N_NODES);
}